// Round 10
// baseline (1762.846 us; speedup 1.0000x reference)
//
#include <hip/hip_runtime.h>
#include <hip/hip_bf16.h>
#include <math.h>

#define DEV static __device__ __forceinline__

typedef __attribute__((ext_vector_type(8))) short short8;
typedef __attribute__((ext_vector_type(4))) float floatx4;

DEV float bf2f(const __hip_bfloat16 v) { return __bfloat162float(v); }
DEV float bfu2f(unsigned short u) { return __uint_as_float((unsigned)u << 16); }

DEV unsigned short f2bf(float v) {   // RNE f32 -> bf16 bits
    unsigned int b = __float_as_uint(v);
    unsigned int r = (b + 0x7FFFu + ((b >> 16) & 1u)) >> 16;
    return (unsigned short)r;
}

DEV float mishf(float x) {
    float sp = fmaxf(x, 0.0f) + log1pf(expf(-fabsf(x)));
    float t = expf(-2.0f * sp);
    return x * (1.0f - t) / (1.0f + t);
}

#define N_T 32
struct Tab {
    const void* src[N_T];
    long long   dstoff[N_T];
    int         n[N_T];
    int         isw[N_T];
    int         cin[N_T];
    int         kk[N_T];
};

// ---------------- per-array dtype detection ----------------
__global__ __launch_bounds__(256) void k_detect(Tab t, int* __restrict__ flags) {
    int i = blockIdx.x;
    int n = t.n[i];
    int m = n < 16384 ? n : 16384;
    const unsigned short* p = (const unsigned short*)t.src[i];
    __shared__ int sInf, sExt, sZero;
    if (threadIdx.x == 0) { sInf = 0; sExt = 0; sZero = 0; }
    __syncthreads();
    int cInf = 0, cExt = 0, cZero = 0;
    for (int j = threadIdx.x; j < m; j += 256) {
        unsigned short h = p[j];
        if ((h & 0x7F80) == 0x7F80) cInf++;
        if ((j & 1) == 0) {
            if (h == 0) cZero++;
            else { int e = (h >> 7) & 0xFF; if (e < 56 || e > 184) cExt++; }
        }
    }
    if (cInf)  atomicAdd(&sInf, cInf);
    if (cExt)  atomicAdd(&sExt, cExt);
    if (cZero) atomicAdd(&sZero, cZero);
    __syncthreads();
    if (threadIdx.x == 0) {
        int nEven = (m + 1) >> 1;
        flags[i] = (sInf > 0 || sExt > 0 || (nEven > 0 && sZero == nEven)) ? 2 : 0;
    }
}

__global__ void k_flag_final(Tab t, int* __restrict__ flags, int xi) {
    if (threadIdx.x == 0 && blockIdx.x == 0) {
        int xf = (flags[xi] == 2) ? 1 : 0;
        for (int i = 0; i < N_T; ++i) {
            int f;
            if (flags[i] == 2)       f = 1;
            else if (t.n[i] >= 256)  f = 0;
            else                     f = xf;
            flags[i] = f;
        }
    }
}

// convert: conv weights -> bf16 WB, layout [co][dy][dx][ci]; others -> f32 PF
__global__ __launch_bounds__(256) void k_convert(
        Tab t, float* __restrict__ pf, unsigned short* __restrict__ wb,
        const int* __restrict__ flags) {
    long long idx = (long long)blockIdx.x * 256 + threadIdx.x;
    long long off = 0;
    #pragma unroll 1
    for (int i = 0; i < N_T; ++i) {
        long long ni = t.n[i];
        if (idx < off + ni) {
            int j = (int)(idx - off);
            float v = flags[i] ? ((const float*)t.src[i])[j]
                               : bf2f(((const __hip_bfloat16*)t.src[i])[j]);
            if (t.isw[i]) {
                int cin = t.cin[i], kk = t.kk[i];
                int ckk = cin * kk;
                int co = j / ckk;
                int rem = j - co * ckk;
                int ci = rem / kk;
                int tt = rem - ci * kk;
                wb[t.dstoff[i] + (size_t)co * ckk + tt * cin + ci] = f2bf(v);
            } else {
                pf[t.dstoff[i] + j] = v;
            }
            return;
        }
        off += ni;
    }
}

// ------- dynamic per-sample conv (k=4, pad=1) + mish -> NHWC bf16 -----------
// One thread per output pixel computes all 32 co; per-sample weights in LDS.
__global__ __launch_bounds__(256) void k_dynconv_mish(
        const float* __restrict__ x, const float* __restrict__ w,
        unsigned short* __restrict__ out) {
    __shared__ float wsm[512];
    int tid = threadIdx.x, b = blockIdx.y;
    wsm[tid]       = w[(b << 9) + tid];
    wsm[tid + 256] = w[(b << 9) + 256 + tid];
    __syncthreads();
    int p = blockIdx.x * 256 + tid;
    if (p >= 255 * 255) return;
    int yo = p / 255, xo = p - yo * 255;
    const float* xp = x + ((size_t)b << 16);
    float a[4][4];
    #pragma unroll
    for (int ky = 0; ky < 4; ++ky) {
        int iy = yo + ky - 1;
        bool yk = (unsigned)iy < 256u;
        #pragma unroll
        for (int kx = 0; kx < 4; ++kx) {
            int ix = xo + kx - 1;
            a[ky][kx] = (yk && (unsigned)ix < 256u) ? xp[(iy << 8) + ix] : 0.f;
        }
    }
    unsigned short* ob = out + ((size_t)b * 65025 + p) * 32;
    #pragma unroll
    for (int g = 0; g < 8; ++g) {
        ushort4 o;
        #pragma unroll
        for (int r = 0; r < 4; ++r) {
            const float* wp = &wsm[(g * 4 + r) * 16];
            float acc = 0.f;
            #pragma unroll
            for (int ky = 0; ky < 4; ++ky)
                #pragma unroll
                for (int kx = 0; kx < 4; ++kx)
                    acc = fmaf(a[ky][kx], wp[ky * 4 + kx], acc);
            ((unsigned short*)&o)[r] = f2bf(mishf(acc));
        }
        *(ushort4*)(ob + g * 4) = o;
    }
}

// ============ NHWC MFMA conv, 128co x 128px block (KS=3, Co%128==0) =========
// 4 waves in 2x2; each wave 64co x 64px -> 16 MFMA per 32-k step.
__global__ __launch_bounds__(256) void k_conv_mfma128(
        const unsigned short* __restrict__ s0, int C0,
        const unsigned short* __restrict__ s1, int C1,
        const unsigned short* __restrict__ wgt,
        const float* __restrict__ bias,
        unsigned short* __restrict__ out,
        int Hin, int Win, int lgW, int lgHW, int Co) {
    __shared__ __align__(16) unsigned short ldsA[128 * 40];
    __shared__ __align__(16) unsigned short ldsB[128 * 40];
    const int tid = threadIdx.x, lane = tid & 63, wv = tid >> 6;
    const int m = lane & 15, quad = lane >> 4;
    const int wr = wv >> 1, wc = wv & 1;
    const int W = 1 << lgW, HW = 1 << lgHW;
    const int C = C0 + C1;
    const int Ktot = 9 * C;
    const int pixbase = blockIdx.x * 128, cobase = blockIdx.y * 128;

    const int seg = tid & 3, ci8 = seg * 8;
    const int row0 = tid >> 2;                 // 0..63
    const int px0 = pixbase + row0, px1 = px0 + 64;
    const int b0 = px0 >> lgHW, pp0 = px0 & (HW - 1);
    const int y0 = pp0 >> lgW, x0 = pp0 & (W - 1);
    const int b1 = px1 >> lgHW, pp1 = px1 & (HW - 1);
    const int y1 = pp1 >> lgW, x1 = pp1 & (W - 1);

    const unsigned short* wA0 = wgt + (size_t)(cobase + row0) * Ktot + ci8;
    const unsigned short* wA1 = wA0 + (size_t)64 * Ktot;

    floatx4 acc[4][4];
    #pragma unroll
    for (int q = 0; q < 4; ++q)
        #pragma unroll
        for (int t = 0; t < 4; ++t) acc[q][t] = (floatx4){0.f, 0.f, 0.f, 0.f};

    for (int dy = 0; dy < 3; ++dy) {
        int iy0 = y0 + dy - 1, iy1 = y1 + dy - 1;
        bool yk0 = (unsigned)iy0 < (unsigned)Hin;
        bool yk1 = (unsigned)iy1 < (unsigned)Hin;
        for (int dx = 0; dx < 3; ++dx) {
            int ix0 = x0 + dx - 1, ix1 = x1 + dx - 1;
            bool ok0 = yk0 && (unsigned)ix0 < (unsigned)Win;
            bool ok1 = yk1 && (unsigned)ix1 < (unsigned)Win;
            long long sb0 = ((long long)b0 * Hin + iy0) * Win + ix0;
            long long sb1 = ((long long)b1 * Hin + iy1) * Win + ix1;
            for (int cs = 0; cs < C; cs += 32) {
                uint4 a0 = *(const uint4*)wA0;
                uint4 a1 = *(const uint4*)wA1;
                uint4 v0 = {0u,0u,0u,0u}, v1 = {0u,0u,0u,0u};
                if (ok0) {
                    const unsigned short* sp = (cs < C0)
                        ? s0 + (size_t)sb0 * C0 + cs + ci8
                        : s1 + (size_t)sb0 * C1 + (cs - C0) + ci8;
                    v0 = *(const uint4*)sp;
                }
                if (ok1) {
                    const unsigned short* sp = (cs < C0)
                        ? s0 + (size_t)sb1 * C0 + cs + ci8
                        : s1 + (size_t)sb1 * C1 + (cs - C0) + ci8;
                    v1 = *(const uint4*)sp;
                }
                *(uint4*)&ldsA[row0 * 40 + ci8]        = a0;
                *(uint4*)&ldsA[(row0 + 64) * 40 + ci8] = a1;
                *(uint4*)&ldsB[row0 * 40 + ci8]        = v0;
                *(uint4*)&ldsB[(row0 + 64) * 40 + ci8] = v1;
                __syncthreads();
                short8 bfr[4], afr[4];
                #pragma unroll
                for (int t = 0; t < 4; ++t)
                    bfr[t] = *(const short8*)&ldsB[(wc * 64 + t * 16 + m) * 40 + quad * 8];
                #pragma unroll
                for (int q = 0; q < 4; ++q)
                    afr[q] = *(const short8*)&ldsA[(wr * 64 + q * 16 + m) * 40 + quad * 8];
                #pragma unroll
                for (int q = 0; q < 4; ++q)
                    #pragma unroll
                    for (int t = 0; t < 4; ++t)
                        acc[q][t] = __builtin_amdgcn_mfma_f32_16x16x32_bf16(
                            afr[q], bfr[t], acc[q][t], 0, 0, 0);
                __syncthreads();
                wA0 += 32; wA1 += 32;
            }
        }
    }
    // epilogue
    #pragma unroll
    for (int t = 0; t < 4; ++t) {
        int px = pixbase + wc * 64 + t * 16 + m;
        int bO = px >> lgHW, pO = px & (HW - 1);
        unsigned short* ob = out + ((size_t)bO * HW + pO) * Co;
        #pragma unroll
        for (int q = 0; q < 4; ++q) {
            int co = cobase + wr * 64 + q * 16 + quad * 4;
            ushort4 o;
            o.x = f2bf(mishf(acc[q][t][0] + bias[co + 0]));
            o.y = f2bf(mishf(acc[q][t][1] + bias[co + 1]));
            o.z = f2bf(mishf(acc[q][t][2] + bias[co + 2]));
            o.w = f2bf(mishf(acc[q][t][3] + bias[co + 3]));
            *(ushort4*)(ob + co) = o;
        }
    }
}

// ============ NHWC MFMA conv, MB co x 64 px (small-Co layers) ================
template<int KS, int MB>
__global__ __launch_bounds__(256) void k_conv_mfma(
        const unsigned short* __restrict__ s0, int C0,
        const unsigned short* __restrict__ s1, int C1,
        const unsigned short* __restrict__ wgt,
        const float* __restrict__ bias,
        unsigned short* __restrict__ out,
        int Hin, int Win, int lgW, int lgHW, int Co) {
    constexpr int PAD = (KS == 3) ? 1 : 2;
    __shared__ __align__(16) unsigned short ldsA[MB * 40];
    __shared__ __align__(16) unsigned short ldsB[64 * 40];
    const int tid = threadIdx.x, lane = tid & 63, wv = tid >> 6;
    const int m = lane & 15, quad = lane >> 4;
    const int W = 1 << lgW, HW = 1 << lgHW;
    const int C = C0 + C1;
    const int Ktot = KS * KS * C;
    const int pixbase = blockIdx.x * 64, cobase = blockIdx.y * MB;

    const int pl = tid >> 2, ci8 = (tid & 3) * 8;
    const int pxs = pixbase + pl;
    const int bS = pxs >> lgHW, ppS = pxs & (HW - 1);
    const int yS = ppS >> lgW, xS = ppS & (W - 1);

    const bool aok = (tid >> 2) < MB;
    const int co_r = aok ? (tid >> 2) : (MB - 1);
    const int seg = tid & 3;
    const unsigned short* wA = wgt + (size_t)(cobase + co_r) * Ktot + seg * 8;

    floatx4 acc[MB / 16];
    #pragma unroll
    for (int q = 0; q < MB / 16; ++q) acc[q] = (floatx4){0.f, 0.f, 0.f, 0.f};

    for (int dy = 0; dy < KS; ++dy) {
        int iy = yS + dy - PAD;
        bool yok = (iy >= 0) && (iy < Hin);
        for (int dx = 0; dx < KS; ++dx) {
            int ix = xS + dx - PAD;
            bool ok = yok && (ix >= 0) && (ix < Win);
            long long sb = ((long long)bS * Hin + iy) * Win + ix;
            for (int cs = 0; cs < C; cs += 32) {
                uint4 a4;
                if (aok) a4 = *(const uint4*)wA;
                uint4 b4 = {0u, 0u, 0u, 0u};
                if (ok) {
                    const unsigned short* sp = (cs < C0)
                        ? s0 + (size_t)sb * C0 + cs + ci8
                        : s1 + (size_t)sb * C1 + (cs - C0) + ci8;
                    b4 = *(const uint4*)sp;
                }
                *(uint4*)&ldsB[pl * 40 + ci8] = b4;
                if (aok) *(uint4*)&ldsA[co_r * 40 + seg * 8] = a4;
                __syncthreads();
                short8 bv = *(const short8*)&ldsB[(wv * 16 + m) * 40 + quad * 8];
                #pragma unroll
                for (int q = 0; q < MB / 16; ++q) {
                    short8 av = *(const short8*)&ldsA[(q * 16 + m) * 40 + quad * 8];
                    acc[q] = __builtin_amdgcn_mfma_f32_16x16x32_bf16(av, bv, acc[q], 0, 0, 0);
                }
                __syncthreads();
                wA += 32;
            }
        }
    }
    const int pxo = pixbase + wv * 16 + m;
    const int bO = pxo >> lgHW, pO = pxo & (HW - 1);
    unsigned short* obase = out + ((size_t)bO * HW + pO) * Co;
    #pragma unroll
    for (int q = 0; q < MB / 16; ++q) {
        int co = cobase + q * 16 + quad * 4;
        ushort4 o;
        o.x = f2bf(mishf(acc[q][0] + bias[co + 0]));
        o.y = f2bf(mishf(acc[q][1] + bias[co + 1]));
        o.z = f2bf(mishf(acc[q][2] + bias[co + 2]));
        o.w = f2bf(mishf(acc[q][3] + bias[co + 3]));
        *(ushort4*)(obase + co) = o;
    }
}

// ---------------- 2x2 maxpool stride 2 (NHWC bf16, square pow2) -------------
__global__ __launch_bounds__(256) void k_maxpool(
        const unsigned short* __restrict__ in, unsigned short* __restrict__ out,
        int lgWin, int lgC, int total) {
    int idx = blockIdx.x * 256 + threadIdx.x;
    if (idx >= total) return;
    int C = 1 << lgC, Wo = 1 << (lgWin - 1);
    int c = idx & (C - 1); int t = idx >> lgC;
    int xo = t & (Wo - 1); t >>= (lgWin - 1);
    int yo = t & (Wo - 1); int b = t >> (lgWin - 1);
    size_t base = ((((size_t)(b << lgWin) + 2 * yo) << lgWin) + 2 * xo) << lgC;
    size_t dc = (size_t)1 << lgC, dr = (size_t)1 << (lgWin + lgC);
    float v0 = bfu2f(in[base + c]);
    float v1 = bfu2f(in[base + dc + c]);
    float v2 = bfu2f(in[base + dr + c]);
    float v3 = bfu2f(in[base + dr + dc + c]);
    out[idx] = f2bf(fmaxf(fmaxf(v0, v1), fmaxf(v2, v3)));
}

// ---------------- batchnorm (batch stats) on NHWC (4,32,32,512) bf16 --------
__global__ __launch_bounds__(256) void k_bn_reduce(
        const unsigned short* __restrict__ in, float* __restrict__ stats) {
    __shared__ float ls[4], ls2[4];
    int c = blockIdx.x;
    int tid = threadIdx.x;
    float s = 0.f, s2 = 0.f;
    for (int i = tid; i < 4096; i += 256) {
        float v = bfu2f(in[(size_t)i * 512 + c]);
        s += v; s2 += v * v;
    }
    #pragma unroll
    for (int off = 32; off; off >>= 1) {
        s  += __shfl_down(s, off, 64);
        s2 += __shfl_down(s2, off, 64);
    }
    if ((tid & 63) == 0) { ls[tid >> 6] = s; ls2[tid >> 6] = s2; }
    __syncthreads();
    if (tid == 0) {
        s  = ls[0] + ls[1] + ls[2] + ls[3];
        s2 = ls2[0] + ls2[1] + ls2[2] + ls2[3];
        float mean = s * (1.f / 4096.f);
        float var  = fmaxf(s2 * (1.f / 4096.f) - mean * mean, 0.f);
        stats[c]       = mean;
        stats[512 + c] = rsqrtf(var + 1e-5f);
    }
}

__global__ __launch_bounds__(256) void k_bn_apply(
        unsigned short* __restrict__ data, const float* __restrict__ stats,
        const float* __restrict__ g, const float* __restrict__ be, int total) {
    int idx = blockIdx.x * 256 + threadIdx.x;
    if (idx >= total) return;
    int c = idx & 511;
    float v = bfu2f(data[idx]);
    data[idx] = f2bf(g[c] * (v - stats[c]) * stats[512 + c] + be[c]);
}

// -------- bilinear x2 upsample, align_corners=True, NHWC bf16, square pow2 ---
__global__ __launch_bounds__(256) void k_up2(
        const unsigned short* __restrict__ in, unsigned short* __restrict__ out,
        int lgW, int lgC, int total) {
    int idx = blockIdx.x * 256 + threadIdx.x;
    if (idx >= total) return;
    int H = 1 << lgW, C = 1 << lgC;
    int c = idx & (C - 1); int t = idx >> lgC;
    int xo = t & (2 * H - 1); t >>= (lgW + 1);
    int yo = t & (2 * H - 1); int b = t >> (lgW + 1);
    float sc = (float)(H - 1) / (float)(2 * H - 1);
    float sy = yo * sc, sx = xo * sc;
    int y0 = (int)sy; int y1 = min(y0 + 1, H - 1); float fy = sy - (float)y0;
    int x0 = (int)sx; int x1 = min(x0 + 1, H - 1); float fx = sx - (float)x0;
    size_t bb = (size_t)b << (2 * lgW);
    size_t i00 = (((bb + ((size_t)y0 << lgW) + x0)) << lgC) + c;
    size_t i01 = (((bb + ((size_t)y0 << lgW) + x1)) << lgC) + c;
    size_t i10 = (((bb + ((size_t)y1 << lgW) + x0)) << lgC) + c;
    size_t i11 = (((bb + ((size_t)y1 << lgW) + x1)) << lgC) + c;
    float a  = bfu2f(in[i00]) * (1.f - fx) + bfu2f(in[i01]) * fx;
    float b2 = bfu2f(in[i10]) * (1.f - fx) + bfu2f(in[i11]) * fx;
    out[idx] = f2bf(a * (1.f - fy) + b2 * fy);
}

// ---------------- final 1x1 conv, NHWC(4,256,256,32) bf16 -> f32 ------------
__global__ __launch_bounds__(256) void k_final1x1(
        const unsigned short* __restrict__ in, const float* __restrict__ wl,
        const float* __restrict__ bl, float* __restrict__ out) {
    int idx = blockIdx.x * 256 + threadIdx.x;
    if (idx >= 4 * 256 * 256) return;
    const unsigned short* p = in + (size_t)idx * 32;
    float acc = bl[0];
    #pragma unroll
    for (int ci = 0; ci < 32; ++ci)
        acc = fmaf(bfu2f(p[ci]), wl[ci], acc);
    out[idx] = acc;
}

static inline int nblk(long long n) { return (int)((n + 255) / 256); }

extern "C" void kernel_launch(void* const* d_in, const int* in_sizes, int n_in,
                              void* d_out, int out_size, void* d_ws, size_t ws_size,
                              hipStream_t stream) {
    static const int EXP_SZ[N_T] = {
        262144, 2048, 16384, 32, 36864, 128, 147456, 128,
        294912, 256, 589824, 256, 1179648, 512, 2359296, 512,
        512, 512, 1769472, 256, 589824, 256, 442368, 128,
        147456, 128, 46080, 32, 9216, 32, 32, 1 };
    static const int ISW[N_T] = {
        0,0,1,0, 1,0,1,0, 1,0,1,0, 1,0,1,0,
        0,0, 1,0,1,0, 1,0,1,0, 1,0,1,0, 0,0 };
    static const int CIN[N_T] = {
        0,0,32,0, 32,0,128,0, 128,0,256,0, 256,0,512,0,
        0,0, 768,0,256,0, 384,0,128,0, 160,0,32,0, 0,0 };
    static const int KKA[N_T] = {
        0,0,16,0, 9,0,9,0, 9,0,9,0, 9,0,9,0,
        0,0, 9,0,9,0, 9,0,9,0, 9,0,9,0, 0,0 };
    int o = -1;
    for (int s = 0; s + N_T <= n_in; ++s) {
        bool ok = true;
        for (int j = 0; j < N_T; ++j)
            if (in_sizes[s + j] != EXP_SZ[j]) { ok = false; break; }
        if (ok) { o = s; break; }
    }
    if (o < 0) return;

    float* ws = (float*)d_ws;
    const long long PFN   = 270336;
    const long long C1o   = PFN;
    const long long C2o   = C1o + 8388608;
    const long long C3o   = C2o + 8388608;
    const long long Po    = C3o + 4194304;
    const long long Qo    = Po  + 8388608;
    const long long STo   = Qo  + 8388608;
    const long long FLo   = STo + 1024;
    const long long WBo   = FLo + 64;
    const long long WBN   = 7628800;
    const size_t NEED = (size_t)WBo * 4 + WBN * 2 + 256;
    if (ws_size < NEED) return;

    float* PF = ws;
    unsigned short* C1 = (unsigned short*)(ws + C1o);
    unsigned short* C2 = (unsigned short*)(ws + C2o);
    unsigned short* C3 = (unsigned short*)(ws + C3o);
    unsigned short* P  = (unsigned short*)(ws + Po);
    unsigned short* Q  = (unsigned short*)(ws + Qo);
    float* ST = ws + STo;
    int* FLAGS = (int*)(ws + FLo);
    unsigned short* WB = (unsigned short*)(ws + WBo);

    Tab tab;
    long long foff = 0, woff = 0, total = 0;
    const float* fp[N_T];
    const unsigned short* wbp[N_T];
    for (int i = 0; i < N_T; ++i) {
        tab.src[i] = d_in[o + i];
        tab.n[i]   = in_sizes[o + i];
        tab.isw[i] = ISW[i];
        tab.cin[i] = CIN[i];
        tab.kk[i]  = KKA[i];
        if (ISW[i]) { tab.dstoff[i] = woff; wbp[i] = WB + woff; fp[i] = nullptr; woff += tab.n[i]; }
        else        { tab.dstoff[i] = foff; fp[i] = PF + foff; wbp[i] = nullptr; foff += tab.n[i]; }
        total += tab.n[i];
    }
    if (foff > PFN || woff > WBN) return;

    const float* xf  = fp[0];  const float* wf = fp[1];
    const unsigned short* d1w = wbp[2];  const float* d1b = fp[3];
    const unsigned short* w2a = wbp[4];  const float* b2a = fp[5];
    const unsigned short* w2b = wbp[6];  const float* b2b = fp[7];
    const unsigned short* w3a = wbp[8];  const float* b3a = fp[9];
    const unsigned short* w3b = wbp[10]; const float* b3b = fp[11];
    const unsigned short* w4a = wbp[12]; const float* b4a = fp[13];
    const unsigned short* w4b = wbp[14]; const float* b4b = fp[15];
    const float* g4 = fp[16], *be4 = fp[17];
    const unsigned short* u3aw = wbp[18]; const float* ub3a = fp[19];
    const unsigned short* u3bw = wbp[20]; const float* ub3b = fp[21];
    const unsigned short* u2aw = wbp[22]; const float* ub2a = fp[23];
    const unsigned short* u2bw = wbp[24]; const float* ub2b = fp[25];
    const unsigned short* u1aw = wbp[26]; const float* ub1a = fp[27];
    const unsigned short* u1bw = wbp[28]; const float* ub1b = fp[29];
    const float* wl = fp[30], *bl = fp[31];
    float* outp = (float*)d_out;

    dim3 blk(256);
    long long n;

    k_detect<<<N_T, blk, 0, stream>>>(tab, FLAGS);
    k_flag_final<<<1, 64, 0, stream>>>(tab, FLAGS, 0);
    k_convert<<<nblk(total), blk, 0, stream>>>(tab, PF, WB, FLAGS);

    // ---- encoder (NHWC bf16 feature maps) ----
    k_dynconv_mish<<<dim3(255, 4), blk, 0, stream>>>(xf, wf, P);
    // d1: k=4 pad=2, P (4,255,255,32) -> C1 (4,256,256,32)   (Co=32 path)
    k_conv_mfma<4, 32><<<dim3(4096, 1), blk, 0, stream>>>(
        P, 32, nullptr, 0, d1w, d1b, C1, 255, 255, 8, 16, 32);
    n = 4ll * 128 * 128 * 32;
    k_maxpool<<<nblk(n), blk, 0, stream>>>(C1, Q, 8, 5, (int)n);
    // c2a: 32->128 @128^2 (N=65536)
    k_conv_mfma128<<<dim3(512, 1), blk, 0, stream>>>(
        Q, 32, nullptr, 0, w2a, b2a, P, 128, 128, 7, 14, 128);
    k_conv_mfma128<<<dim3(512, 1), blk, 0, stream>>>(
        P, 128, nullptr, 0, w2b, b2b, C2, 128, 128, 7, 14, 128);
    n = 4ll * 64 * 64 * 128;
    k_maxpool<<<nblk(n), blk, 0, stream>>>(C2, Q, 7, 7, (int)n);
    // c3a: 128->256 @64^2 (N=16384)
    k_conv_mfma128<<<dim3(128, 2), blk, 0, stream>>>(
        Q, 128, nullptr, 0, w3a, b3a, P, 64, 64, 6, 12, 256);
    k_conv_mfma128<<<dim3(128, 2), blk, 0, stream>>>(
        P, 256, nullptr, 0, w3b, b3b, C3, 64, 64, 6, 12, 256);
    n = 4ll * 32 * 32 * 256;
    k_maxpool<<<nblk(n), blk, 0, stream>>>(C3, Q, 6, 8, (int)n);
    // c4a: 256->512 @32^2 (N=4096)
    k_conv_mfma128<<<dim3(32, 4), blk, 0, stream>>>(
        Q, 256, nullptr, 0, w4a, b4a, P, 32, 32, 5, 10, 512);
    k_conv_mfma128<<<dim3(32, 4), blk, 0, stream>>>(
        P, 512, nullptr, 0, w4b, b4b, Q, 32, 32, 5, 10, 512);
    n = 4ll * 32 * 32 * 512;
    k_bn_reduce<<<512, blk, 0, stream>>>(Q, ST);
    k_bn_apply<<<nblk(n), blk, 0, stream>>>(Q, ST, g4, be4, (int)n);

    // ---- decoder ----
    // stage 3: up2 Q (4,32,32,512) -> P (4,64,64,512)
    n = 4ll * 64 * 64 * 512;
    k_up2<<<nblk(n), blk, 0, stream>>>(Q, P, 5, 9, (int)n);
    // u3a: [P:512 | C3:256] -> Q (4,64,64,256)
    k_conv_mfma128<<<dim3(128, 2), blk, 0, stream>>>(
        P, 512, C3, 256, u3aw, ub3a, Q, 64, 64, 6, 12, 256);
    k_conv_mfma128<<<dim3(128, 2), blk, 0, stream>>>(
        Q, 256, nullptr, 0, u3bw, ub3b, P, 64, 64, 6, 12, 256);

    // stage 2 per batch: up2(P_b (64,64,256)) -> U2(=C3 region), conv -> Q_b
    unsigned short* U2 = C3;
    for (int b = 0; b < 4; ++b) {
        k_up2<<<nblk(4194304), blk, 0, stream>>>(P + (size_t)b * 1048576, U2,
                                                 6, 8, 4194304);
        k_conv_mfma128<<<dim3(128, 1), blk, 0, stream>>>(
            U2, 256, C2 + (size_t)b * 2097152, 128, u2aw, ub2a,
            Q + (size_t)b * 2097152, 128, 128, 7, 14, 128);
    }
    // u2b: Q (4,128,128,128) -> P
    k_conv_mfma128<<<dim3(512, 1), blk, 0, stream>>>(
        Q, 128, nullptr, 0, u2bw, ub2b, P, 128, 128, 7, 14, 128);

    // stage 1 per batch: up2(P_b (128,128,128)) -> U1(=C2 region), conv -> Q_b
    unsigned short* U1 = C2;
    for (int b = 0; b < 4; ++b) {
        k_up2<<<nblk(8388608), blk, 0, stream>>>(P + (size_t)b * 2097152, U1,
                                                 7, 7, 8388608);
        k_conv_mfma<3, 32><<<dim3(1024, 1), blk, 0, stream>>>(
            U1, 128, C1 + (size_t)b * 2097152, 32, u1aw, ub1a,
            Q + (size_t)b * 2097152, 256, 256, 8, 16, 32);
    }
    // u1b: Q (4,256,256,32) -> P
    k_conv_mfma<3, 32><<<dim3(4096, 1), blk, 0, stream>>>(
        Q, 32, nullptr, 0, u1bw, ub1b, P, 256, 256, 8, 16, 32);

    // final 1x1 -> f32 out
    n = 4ll * 256 * 256;
    k_final1x1<<<nblk(n), blk, 0, stream>>>(P, wl, bl, outp);
}